// Round 10
// baseline (2374.658 us; speedup 1.0000x reference)
//
#include <hip/hip_runtime.h>
#include <hip/hip_bf16.h>

// THLSTM cell fused, MI355X gfx950 — round 10.
// Round-6 shape, spill-free: BT=128, 8 waves, wave = 64 rows x 64 cols
// (4 accs, 4 MFMA per 2A+2B loads). 160KB LDS = 4 regions x [hx k8 0..47 |
// s k8 48..79] -> one contiguous K=640 A-stream. Register trims vs round 6:
// no spk (s re-read from LDS), cacc packed bf16 (cpk), rings depth 2.
// Demand ~200 arch + 64 agpr < 256 cap (launch_bounds(512,2)) -> no spill.

constexpr int Btot = 65536;
constexpr int H    = 256;
constexpr int I    = 128;
constexpr int K1   = 384;    // [h|x]
constexpr int BT   = 128;    // batch rows per WG
constexpr int NTHR = 512;    // 8 waves
constexpr int REG1 = 40960;  // per-32-row region: 80 k8 x 32 rows x 16B

typedef __bf16 bf16x8  __attribute__((ext_vector_type(8)));
typedef float  f32x16  __attribute__((ext_vector_type(16)));
typedef unsigned short ushort8 __attribute__((ext_vector_type(8)));

__device__ __forceinline__ unsigned short f2bf(float f) {
    unsigned u = __builtin_bit_cast(unsigned, f);
    u += 0x7fffu + ((u >> 16) & 1u);   // RNE
    return (unsigned short)(u >> 16);
}
__device__ __forceinline__ float bf2f(unsigned short s) {
    return __builtin_bit_cast(float, ((unsigned)s) << 16);
}
__device__ __forceinline__ float sigm(float x) {
    return __builtin_amdgcn_rcpf(1.0f + exp2f(-1.4426950408889634f * x));
}
__device__ __forceinline__ float tanh_f(float x) {
    return 1.0f - 2.0f * __builtin_amdgcn_rcpf(1.0f + exp2f(2.8853900817779268f * x));
}

// Weights to bf16, layout [k8][col][8]: elem (col, k=k8*8+e) at (k8*256+col)*8+e.
// w0: 48 k8 (K=384); per gate wg: 80 k8 (K=640: h|x|s), gates f,i,T,u,o.
__global__ void convert_w(const float* __restrict__ Wh, const float* __restrict__ Wx,
                          const float* __restrict__ Ws, unsigned short* __restrict__ w0,
                          unsigned short* __restrict__ wg) {
    const int t  = blockIdx.x * blockDim.x + threadIdx.x;
    const int N0 = 48 * 2048;        // 98304
    const int N1 = 5 * 80 * 2048;    // 819200
    if (t < N0) {
        const int k8 = t >> 11, rem = t & 2047;
        const int col = rem >> 3, e = rem & 7;
        const int k = k8 * 8 + e;
        const float v = (k < H) ? Wh[col * H + k] : Wx[col * I + (k - H)];
        w0[t] = f2bf(v);
    } else if (t < N0 + N1) {
        const int u   = t - N0;
        const int g1  = u / 163840;
        const int rem = u - g1 * 163840;
        const int k8  = rem >> 11;
        const int r2  = rem & 2047;
        const int col = r2 >> 3, e = r2 & 7;
        const int k   = k8 * 8 + e;
        const int g   = g1 + 1;
        float v;
        if (k < H)        v = Wh[g * H * H + col * H + k];
        else if (k < K1)  v = Wx[g * H * I + col * I + (k - H)];
        else              v = Ws[g1 * H * H + col * H + (k - K1)];
        wg[u] = f2bf(v);
    }
}

// 2 A streams (row regions) x 2 B streams (col tiles) -> 4 MFMAs/iter.
// All rings depth 2, fully static indexing.
template<int NIT>
__device__ __forceinline__ void gemm4(const unsigned char* Ab, int a0off, int a1off,
        const unsigned short* __restrict__ Wp,
        f32x16& c00, f32x16& c01, f32x16& c10, f32x16& c11) {
    bf16x8 a0[2], a1[2], b0[2], b1[2];
    #pragma unroll
    for (int i = 0; i < 2; ++i) {
        a0[i] = *(const bf16x8*)(Ab + a0off + i * 1024);
        a1[i] = *(const bf16x8*)(Ab + a1off + i * 1024);
        b0[i] = *(const bf16x8*)(Wp + i * 4096);
        b1[i] = *(const bf16x8*)(Wp + i * 4096 + 256);
    }
    #pragma unroll
    for (int i = 0; i < NIT; ++i) {
        const bf16x8 av0 = a0[i & 1], av1 = a1[i & 1];
        const bf16x8 bv0 = b0[i & 1], bv1 = b1[i & 1];
        if (i + 2 < NIT) {
            a0[i & 1] = *(const bf16x8*)(Ab + a0off + (i + 2) * 1024);
            a1[i & 1] = *(const bf16x8*)(Ab + a1off + (i + 2) * 1024);
            b0[i & 1] = *(const bf16x8*)(Wp + (i + 2) * 4096);
            b1[i & 1] = *(const bf16x8*)(Wp + (i + 2) * 4096 + 256);
        }
        c00 = __builtin_amdgcn_mfma_f32_32x32x16_bf16(av0, bv0, c00, 0, 0, 0);
        c01 = __builtin_amdgcn_mfma_f32_32x32x16_bf16(av0, bv1, c01, 0, 0, 0);
        c10 = __builtin_amdgcn_mfma_f32_32x32x16_bf16(av1, bv0, c10, 0, 0, 0);
        c11 = __builtin_amdgcn_mfma_f32_32x32x16_bf16(av1, bv1, c11, 0, 0, 0);
    }
}

__global__ __launch_bounds__(NTHR, 2) void thlstm_fused(
        const float* __restrict__ x_t, const float* __restrict__ delta_t,
        const float* __restrict__ h_prev, const float* __restrict__ c_prev,
        const float* __restrict__ Wst, const float* __restrict__ bias,
        const unsigned short* __restrict__ w0, const unsigned short* __restrict__ wg,
        float* __restrict__ out) {
    __shared__ __align__(16) unsigned char Abuf[163840];   // 4 x 40960 regions
    const int tid = threadIdx.x;
    const int b0  = blockIdx.x * BT;

    // ---- stage h|x bf16: region(row>>5), chunk (k8, row&31) at (k8*32+row31)*16
    #pragma unroll
    for (int it = 0; it < 12; ++it) {
        const int c   = it * NTHR + tid;
        const int k8  = c >> 7, row = c & 127;
        const float* src = (k8 < 32) ? (h_prev + (size_t)(b0 + row) * H + k8 * 8)
                                     : (x_t    + (size_t)(b0 + row) * I + (k8 - 32) * 8);
        const float4 v0 = ((const float4*)src)[0];
        const float4 v1 = ((const float4*)src)[1];
        ushort8 p;
        p[0] = f2bf(v0.x); p[1] = f2bf(v0.y); p[2] = f2bf(v0.z); p[3] = f2bf(v0.w);
        p[4] = f2bf(v1.x); p[5] = f2bf(v1.y); p[6] = f2bf(v1.z); p[7] = f2bf(v1.w);
        *(ushort8*)(Abuf + (row >> 5) * REG1 + (k8 * 32 + (row & 31)) * 16) = p;
    }
    __syncthreads();

    const int lane  = tid & 63;
    const int wv    = tid >> 6;
    const int half  = lane >> 5;
    const int l31   = lane & 31;
    const int wr    = wv >> 2;            // rows wr*64 .. wr*64+63
    const int wc    = wv & 3;             // cols wc*64 .. wc*64+63
    const int rbase = 4 * half;
    const int a0    = (2 * wr) * REG1 + half * 512 + l31 * 16;
    const int a1    = a0 + REG1;
    const int wb    = half * 2048 + (wc * 64 + l31) * 8;   // shorts; tile1 = +256

    // ---- gate s: K=384 ----
    {
        f32x16 ac[2][2];
        #pragma unroll
        for (int q = 0; q < 2; ++q)
            #pragma unroll
            for (int p = 0; p < 2; ++p)
                #pragma unroll
                for (int r = 0; r < 16; ++r) ac[q][p][r] = 0.f;
        gemm4<24>(Abuf, a0, a1, w0 + wb, ac[0][0], ac[0][1], ac[1][0], ac[1][1]);
        #pragma unroll
        for (int ct = 0; ct < 2; ++ct) {
            const int col = wc * 64 + ct * 32 + l31;
            const float wst = Wst[col];
            const float bs  = bias[col];
            #pragma unroll
            for (int rt = 0; rt < 2; ++rt)
                #pragma unroll
                for (int r = 0; r < 16; ++r) {
                    const int grow = wr * 64 + rt * 32 + (r & 3) + 8 * (r >> 2) + rbase;
                    const float sv = tanh_f(ac[rt][ct][r] + delta_t[b0 + grow] * wst + bs);
                    *(unsigned short*)(Abuf + (grow >> 5) * REG1 +
                        (48 + (col >> 3)) * 512 + (grow & 31) * 16 + (col & 7) * 2) = f2bf(sv);
                }
        }
    }
    __syncthreads();

    unsigned cpk[2][2][8];   // packed bf16 running c
    unsigned ipk[2][2][8];   // packed bf16 sigm(i)

    // ---- gate f (wg 0, bias 1): c = f * c_prev ----
    {
        f32x16 ac[2][2];
        #pragma unroll
        for (int q = 0; q < 2; ++q)
            #pragma unroll
            for (int p = 0; p < 2; ++p)
                #pragma unroll
                for (int r = 0; r < 16; ++r) ac[q][p][r] = 0.f;
        gemm4<40>(Abuf, a0, a1, wg + 0 * 163840 + wb, ac[0][0], ac[0][1], ac[1][0], ac[1][1]);
        #pragma unroll
        for (int ct = 0; ct < 2; ++ct) {
            const int col = wc * 64 + ct * 32 + l31;
            const float bg = bias[1 * H + col];
            #pragma unroll
            for (int rt = 0; rt < 2; ++rt) {
                float prev = 0.f;
                #pragma unroll
                for (int r = 0; r < 16; ++r) {
                    const int grow = wr * 64 + rt * 32 + (r & 3) + 8 * (r >> 2) + rbase;
                    const size_t idx = (size_t)(b0 + grow) * H + col;
                    const float cv = sigm(ac[rt][ct][r] + bg) * c_prev[idx];
                    if ((r & 1) == 0) prev = cv;
                    else cpk[rt][ct][r >> 1] = (unsigned)f2bf(prev) | ((unsigned)f2bf(cv) << 16);
                }
            }
        }
    }
    // ---- gate T (wg 2, bias 3): c += T * s (s from LDS) ----
    {
        f32x16 ac[2][2];
        #pragma unroll
        for (int q = 0; q < 2; ++q)
            #pragma unroll
            for (int p = 0; p < 2; ++p)
                #pragma unroll
                for (int r = 0; r < 16; ++r) ac[q][p][r] = 0.f;
        gemm4<40>(Abuf, a0, a1, wg + 2 * 163840 + wb, ac[0][0], ac[0][1], ac[1][0], ac[1][1]);
        #pragma unroll
        for (int ct = 0; ct < 2; ++ct) {
            const int col = wc * 64 + ct * 32 + l31;
            const float bg = bias[3 * H + col];
            #pragma unroll
            for (int rt = 0; rt < 2; ++rt) {
                float prev = 0.f;
                #pragma unroll
                for (int r = 0; r < 16; ++r) {
                    const int grow = wr * 64 + rt * 32 + (r & 3) + 8 * (r >> 2) + rbase;
                    const float sv = bf2f(*(const unsigned short*)(Abuf + (grow >> 5) * REG1 +
                        (48 + (col >> 3)) * 512 + (grow & 31) * 16 + (col & 7) * 2));
                    const float co = bf2f((unsigned short)((cpk[rt][ct][r >> 1] >> ((r & 1) * 16)) & 0xffffu));
                    const float cv = co + sigm(ac[rt][ct][r] + bg) * sv;
                    if ((r & 1) == 0) prev = cv;
                    else cpk[rt][ct][r >> 1] = (unsigned)f2bf(prev) | ((unsigned)f2bf(cv) << 16);
                }
            }
        }
    }
    // ---- gate i (wg 1, bias 2): pack sigm(i) ----
    {
        f32x16 ac[2][2];
        #pragma unroll
        for (int q = 0; q < 2; ++q)
            #pragma unroll
            for (int p = 0; p < 2; ++p)
                #pragma unroll
                for (int r = 0; r < 16; ++r) ac[q][p][r] = 0.f;
        gemm4<40>(Abuf, a0, a1, wg + 1 * 163840 + wb, ac[0][0], ac[0][1], ac[1][0], ac[1][1]);
        #pragma unroll
        for (int ct = 0; ct < 2; ++ct) {
            const int col = wc * 64 + ct * 32 + l31;
            const float bg = bias[2 * H + col];
            #pragma unroll
            for (int rt = 0; rt < 2; ++rt) {
                float prev = 0.f;
                #pragma unroll
                for (int r = 0; r < 16; ++r) {
                    const float sg = sigm(ac[rt][ct][r] + bg);
                    if ((r & 1) == 0) prev = sg;
                    else ipk[rt][ct][r >> 1] = (unsigned)f2bf(prev) | ((unsigned)f2bf(sg) << 16);
                }
            }
        }
    }
    // ---- gate u (wg 3, bias 4): c += i * tanh(u) ----
    {
        f32x16 ac[2][2];
        #pragma unroll
        for (int q = 0; q < 2; ++q)
            #pragma unroll
            for (int p = 0; p < 2; ++p)
                #pragma unroll
                for (int r = 0; r < 16; ++r) ac[q][p][r] = 0.f;
        gemm4<40>(Abuf, a0, a1, wg + 3 * 163840 + wb, ac[0][0], ac[0][1], ac[1][0], ac[1][1]);
        #pragma unroll
        for (int ct = 0; ct < 2; ++ct) {
            const int col = wc * 64 + ct * 32 + l31;
            const float bg = bias[4 * H + col];
            #pragma unroll
            for (int rt = 0; rt < 2; ++rt) {
                float prev = 0.f;
                #pragma unroll
                for (int r = 0; r < 16; ++r) {
                    const float iv = bf2f((unsigned short)((ipk[rt][ct][r >> 1] >> ((r & 1) * 16)) & 0xffffu));
                    const float co = bf2f((unsigned short)((cpk[rt][ct][r >> 1] >> ((r & 1) * 16)) & 0xffffu));
                    const float cv = co + iv * tanh_f(ac[rt][ct][r] + bg);
                    if ((r & 1) == 0) prev = cv;
                    else cpk[rt][ct][r >> 1] = (unsigned)f2bf(prev) | ((unsigned)f2bf(cv) << 16);
                }
            }
        }
    }
    // ---- gate o (wg 4, bias 5): outputs ----
    {
        f32x16 ac[2][2];
        #pragma unroll
        for (int q = 0; q < 2; ++q)
            #pragma unroll
            for (int p = 0; p < 2; ++p)
                #pragma unroll
                for (int r = 0; r < 16; ++r) ac[q][p][r] = 0.f;
        gemm4<40>(Abuf, a0, a1, wg + 4 * 163840 + wb, ac[0][0], ac[0][1], ac[1][0], ac[1][1]);
        #pragma unroll
        for (int ct = 0; ct < 2; ++ct) {
            const int col = wc * 64 + ct * 32 + l31;
            const float bg = bias[5 * H + col];
            #pragma unroll
            for (int rt = 0; rt < 2; ++rt)
                #pragma unroll
                for (int r = 0; r < 16; ++r) {
                    const int grow = wr * 64 + rt * 32 + (r & 3) + 8 * (r >> 2) + rbase;
                    const size_t idx = (size_t)(b0 + grow) * H + col;
                    const float c = bf2f((unsigned short)((cpk[rt][ct][r >> 1] >> ((r & 1) * 16)) & 0xffffu));
                    out[idx] = sigm(ac[rt][ct][r] + bg) * tanh_f(c);
                    out[(size_t)Btot * H + idx] = c;
                }
        }
    }
}

extern "C" void kernel_launch(void* const* d_in, const int* in_sizes, int n_in,
                              void* d_out, int out_size, void* d_ws, size_t ws_size,
                              hipStream_t stream) {
    (void)in_sizes; (void)n_in; (void)out_size; (void)ws_size;
    const float* x_t    = (const float*)d_in[0];
    const float* delta  = (const float*)d_in[1];
    const float* h_prev = (const float*)d_in[2];
    const float* c_prev = (const float*)d_in[3];
    const float* Wh     = (const float*)d_in[4];
    const float* Wx     = (const float*)d_in[5];
    const float* Ws     = (const float*)d_in[6];
    const float* Wst    = (const float*)d_in[7];
    const float* bias   = (const float*)d_in[8];
    float* out = (float*)d_out;

    unsigned short* w0 = (unsigned short*)d_ws;   // 48*2048 bf16
    unsigned short* wg = w0 + 48 * 2048;          // 5*80*2048 bf16

    const int total = 48 * 2048 + 5 * 80 * 2048;  // 917504
    convert_w<<<(total + 255) / 256, 256, 0, stream>>>(Wh, Wx, Ws, w0, wg);
    thlstm_fused<<<Btot / BT, NTHR, 0, stream>>>(x_t, delta, h_prev, c_prev,
                                                 Wst, bias, w0, wg, out);
}

// Round 11
// 221.419 us; speedup vs baseline: 10.7247x; 10.7247x over previous
//
#include <hip/hip_runtime.h>
#include <hip/hip_bf16.h>

// THLSTM cell fused, MI355X gfx950 — round 11.
// r9's lean wave (1 acc/wave, arch 64 + agpr 64 regs -> 4 waves/SIMD) scaled
// to BT=64 via 16 waves/WG (NTHR=1024): halves L2 weight traffic vs r9
// (1024 WGs x 1.84 MB = 1.88 GB, ~55us L2 floor). LDS 80KB = 2 regions
// (rows 0-31, 32-63), each [hx k8 0..47 | s k8 48..79] -> K=640 A-stream.

constexpr int Btot = 65536;
constexpr int H    = 256;
constexpr int I    = 128;
constexpr int K1   = 384;    // [h|x]
constexpr int BT   = 64;     // batch rows per WG
constexpr int NTHR = 1024;   // 16 waves
constexpr int REG1 = 40960;  // per-32-row region: 80 k8 x 32 rows x 16B
constexpr int SOFF = 24576;  // s base within region: 48 k8 x 32 x 16B

typedef __bf16 bf16x8  __attribute__((ext_vector_type(8)));
typedef float  f32x16  __attribute__((ext_vector_type(16)));
typedef unsigned short ushort8 __attribute__((ext_vector_type(8)));

__device__ __forceinline__ unsigned short f2bf(float f) {
    unsigned u = __builtin_bit_cast(unsigned, f);
    u += 0x7fffu + ((u >> 16) & 1u);   // RNE
    return (unsigned short)(u >> 16);
}
__device__ __forceinline__ float bf2f(unsigned short s) {
    return __builtin_bit_cast(float, ((unsigned)s) << 16);
}
__device__ __forceinline__ float sigm(float x) {
    return __builtin_amdgcn_rcpf(1.0f + exp2f(-1.4426950408889634f * x));
}
__device__ __forceinline__ float tanh_f(float x) {
    return 1.0f - 2.0f * __builtin_amdgcn_rcpf(1.0f + exp2f(2.8853900817779268f * x));
}

// Weights to bf16, layout [k8][col][8]: elem (col, k=k8*8+e) at (k8*256+col)*8+e.
// w0: 48 k8 (K=384); per gate wg: 80 k8 (K=640: h|x|s), gates f,i,T,u,o.
__global__ void convert_w(const float* __restrict__ Wh, const float* __restrict__ Wx,
                          const float* __restrict__ Ws, unsigned short* __restrict__ w0,
                          unsigned short* __restrict__ wg) {
    const int t  = blockIdx.x * blockDim.x + threadIdx.x;
    const int N0 = 48 * 2048;        // 98304
    const int N1 = 5 * 80 * 2048;    // 819200
    if (t < N0) {
        const int k8 = t >> 11, rem = t & 2047;
        const int col = rem >> 3, e = rem & 7;
        const int k = k8 * 8 + e;
        const float v = (k < H) ? Wh[col * H + k] : Wx[col * I + (k - H)];
        w0[t] = f2bf(v);
    } else if (t < N0 + N1) {
        const int u   = t - N0;
        const int g1  = u / 163840;
        const int rem = u - g1 * 163840;
        const int k8  = rem >> 11;
        const int r2  = rem & 2047;
        const int col = r2 >> 3, e = r2 & 7;
        const int k   = k8 * 8 + e;
        const int g   = g1 + 1;
        float v;
        if (k < H)        v = Wh[g * H * H + col * H + k];
        else if (k < K1)  v = Wx[g * H * I + col * I + (k - H)];
        else              v = Ws[g1 * H * H + col * H + (k - K1)];
        wg[u] = f2bf(v);
    }
}

// K-loop: 1 A stream, 1 B stream, single acc chain. Ring depth 2.
template<int NIT>
__device__ __forceinline__ void gemm1(const unsigned char* Ab, int abase,
        const unsigned short* __restrict__ Wp, f32x16& acc) {
    bf16x8 b[2], a[2];
    #pragma unroll
    for (int i = 0; i < 2; ++i) {
        b[i] = *(const bf16x8*)(Wp + i * 4096);
        a[i] = *(const bf16x8*)(Ab + abase + i * 1024);
    }
    #pragma unroll
    for (int i = 0; i < NIT; ++i) {
        const bf16x8 av = a[i & 1], bv = b[i & 1];
        if (i + 2 < NIT) {
            a[i & 1] = *(const bf16x8*)(Ab + abase + (i + 2) * 1024);
            b[i & 1] = *(const bf16x8*)(Wp + (i + 2) * 4096);
        }
        acc = __builtin_amdgcn_mfma_f32_32x32x16_bf16(av, bv, acc, 0, 0, 0);
    }
}

__global__ __launch_bounds__(NTHR, 4) void thlstm_fused(
        const float* __restrict__ x_t, const float* __restrict__ delta_t,
        const float* __restrict__ h_prev, const float* __restrict__ c_prev,
        const float* __restrict__ Wst, const float* __restrict__ bias,
        const unsigned short* __restrict__ w0, const unsigned short* __restrict__ wg,
        float* __restrict__ out) {
    __shared__ __align__(16) unsigned char Abuf[81920];   // 2 x 40960 regions
    const int tid = threadIdx.x;
    const int b0  = blockIdx.x * BT;

    // ---- stage h|x bf16: region(row>>5), chunk (k8, row&31) ----
    #pragma unroll
    for (int it = 0; it < 3; ++it) {
        const int c   = it * NTHR + tid;
        const int k8  = c >> 6, row = c & 63;
        const float* src = (k8 < 32) ? (h_prev + (size_t)(b0 + row) * H + k8 * 8)
                                     : (x_t    + (size_t)(b0 + row) * I + (k8 - 32) * 8);
        const float4 v0 = ((const float4*)src)[0];
        const float4 v1 = ((const float4*)src)[1];
        ushort8 p;
        p[0] = f2bf(v0.x); p[1] = f2bf(v0.y); p[2] = f2bf(v0.z); p[3] = f2bf(v0.w);
        p[4] = f2bf(v1.x); p[5] = f2bf(v1.y); p[6] = f2bf(v1.z); p[7] = f2bf(v1.w);
        *(ushort8*)(Abuf + (row >> 5) * REG1 + (k8 * 32 + (row & 31)) * 16) = p;
    }
    __syncthreads();

    const int lane  = tid & 63;
    const int wv    = tid >> 6;            // 0..15
    const int rg    = wv >> 3;             // row region 0/1 -> rows rg*32..+31
    const int half  = lane >> 5;
    const int l31   = lane & 31;
    const int ocol  = (wv & 7) * 32 + l31;
    const int rowb  = rg * 32;             // wave's global row base within WG
    const int rbase = 4 * half;
    const int abase = rg * REG1 + half * 512 + l31 * 16;
    const int wlo   = half * 2048 + ocol * 8;   // shorts
    const int sbase = rg * REG1 + SOFF + ((ocol >> 3) * 32) * 16 + (ocol & 7) * 2;

    // ---- gate s: K=384 ----
    {
        f32x16 acc;
        #pragma unroll
        for (int r = 0; r < 16; ++r) acc[r] = 0.f;
        gemm1<24>(Abuf, abase, w0 + wlo, acc);
        const float wst = Wst[ocol];
        const float bs  = bias[ocol];
        #pragma unroll
        for (int r = 0; r < 16; ++r) {
            const int mrow = (r & 3) + 8 * (r >> 2) + rbase;
            const float sv = tanh_f(acc[r] + delta_t[b0 + rowb + mrow] * wst + bs);
            *(unsigned short*)(Abuf + sbase + mrow * 16) = f2bf(sv);
        }
    }
    __syncthreads();

    float    cacc[16];
    unsigned ipk[8];

    // ---- gate f (wg 0, bias 1): c = f * c_prev ----
    {
        f32x16 ac;
        #pragma unroll
        for (int r = 0; r < 16; ++r) ac[r] = 0.f;
        gemm1<40>(Abuf, abase, wg + 0 * 163840 + wlo, ac);
        const float bg = bias[1 * H + ocol];
        #pragma unroll
        for (int r = 0; r < 16; ++r) {
            const int mrow = (r & 3) + 8 * (r >> 2) + rbase;
            const size_t idx = (size_t)(b0 + rowb + mrow) * H + ocol;
            cacc[r] = sigm(ac[r] + bg) * c_prev[idx];
        }
    }
    // ---- gate T (wg 2, bias 3): c += T * s (s from LDS) ----
    {
        f32x16 ac;
        #pragma unroll
        for (int r = 0; r < 16; ++r) ac[r] = 0.f;
        gemm1<40>(Abuf, abase, wg + 2 * 163840 + wlo, ac);
        const float bg = bias[3 * H + ocol];
        #pragma unroll
        for (int r = 0; r < 16; ++r) {
            const int mrow = (r & 3) + 8 * (r >> 2) + rbase;
            const float sv = bf2f(*(const unsigned short*)(Abuf + sbase + mrow * 16));
            cacc[r] += sigm(ac[r] + bg) * sv;
        }
    }
    // ---- gate i (wg 1, bias 2): keep packed ----
    {
        f32x16 ac;
        #pragma unroll
        for (int r = 0; r < 16; ++r) ac[r] = 0.f;
        gemm1<40>(Abuf, abase, wg + 1 * 163840 + wlo, ac);
        const float bg = bias[2 * H + ocol];
        float tmpf = 0.f;
        #pragma unroll
        for (int r = 0; r < 16; ++r) {
            const float sg = sigm(ac[r] + bg);
            if ((r & 1) == 0) tmpf = sg;
            else ipk[r >> 1] = (unsigned)f2bf(tmpf) | ((unsigned)f2bf(sg) << 16);
        }
    }
    // ---- gate u (wg 3, bias 4): c += i * tanh(u) ----
    {
        f32x16 ac;
        #pragma unroll
        for (int r = 0; r < 16; ++r) ac[r] = 0.f;
        gemm1<40>(Abuf, abase, wg + 3 * 163840 + wlo, ac);
        const float bg = bias[4 * H + ocol];
        #pragma unroll
        for (int r = 0; r < 16; ++r) {
            const float iv = bf2f((unsigned short)((ipk[r >> 1] >> ((r & 1) * 16)) & 0xffffu));
            cacc[r] += iv * tanh_f(ac[r] + bg);
        }
    }
    // ---- gate o (wg 4, bias 5): outputs ----
    {
        f32x16 ac;
        #pragma unroll
        for (int r = 0; r < 16; ++r) ac[r] = 0.f;
        gemm1<40>(Abuf, abase, wg + 4 * 163840 + wlo, ac);
        const float bg = bias[5 * H + ocol];
        #pragma unroll
        for (int r = 0; r < 16; ++r) {
            const int mrow = (r & 3) + 8 * (r >> 2) + rbase;
            const size_t idx = (size_t)(b0 + rowb + mrow) * H + ocol;
            const float c = cacc[r];
            out[idx] = sigm(ac[r] + bg) * tanh_f(c);
            out[(size_t)Btot * H + idx] = c;
        }
    }
}

extern "C" void kernel_launch(void* const* d_in, const int* in_sizes, int n_in,
                              void* d_out, int out_size, void* d_ws, size_t ws_size,
                              hipStream_t stream) {
    (void)in_sizes; (void)n_in; (void)out_size; (void)ws_size;
    const float* x_t    = (const float*)d_in[0];
    const float* delta  = (const float*)d_in[1];
    const float* h_prev = (const float*)d_in[2];
    const float* c_prev = (const float*)d_in[3];
    const float* Wh     = (const float*)d_in[4];
    const float* Wx     = (const float*)d_in[5];
    const float* Ws     = (const float*)d_in[6];
    const float* Wst    = (const float*)d_in[7];
    const float* bias   = (const float*)d_in[8];
    float* out = (float*)d_out;

    unsigned short* w0 = (unsigned short*)d_ws;   // 48*2048 bf16
    unsigned short* wg = w0 + 48 * 2048;          // 5*80*2048 bf16

    const int total = 48 * 2048 + 5 * 80 * 2048;  // 917504
    convert_w<<<(total + 255) / 256, 256, 0, stream>>>(Wh, Wx, Ws, w0, wg);
    thlstm_fused<<<Btot / BT, NTHR, 0, stream>>>(x_t, delta, h_prev, c_prev,
                                                 Wst, bias, w0, wg, out);
}

// Round 12
// 219.469 us; speedup vs baseline: 10.8200x; 1.0089x over previous
//
#include <hip/hip_runtime.h>
#include <hip/hip_bf16.h>

// THLSTM cell fused, MI355X gfx950 — round 12.
// r11 lean-wave base + gate-pair fusion: passes (f,T), (i,u), (o) share the
// A-stream; 2 B-streams + 2 MFMAs/iter into 2 AGPR accs (32 AGPR, free —
// arch-64 granule untouched). cacc lives in LDS as bf16 (r10 proved precision),
// ipk eliminated (i,u coexist). LDS 112KB = 80 A-tile + 32 c-tile.
// 16 waves/WG, 4 waves/SIMD, launch_bounds(1024,4).

constexpr int Btot = 65536;
constexpr int H    = 256;
constexpr int I    = 128;
constexpr int K1   = 384;    // [h|x]
constexpr int BT   = 64;     // batch rows per WG
constexpr int NTHR = 1024;   // 16 waves
constexpr int REG1 = 40960;  // per-32-row region: 80 k8 x 32 rows x 16B
constexpr int SOFF = 24576;  // s base within region: 48 k8 x 32 x 16B
constexpr int COFF = 81920;  // c-tile base: 32 col-chunks x 64 rows x 16B

typedef __bf16 bf16x8  __attribute__((ext_vector_type(8)));
typedef float  f32x16  __attribute__((ext_vector_type(16)));
typedef unsigned short ushort8 __attribute__((ext_vector_type(8)));

__device__ __forceinline__ unsigned short f2bf(float f) {
    unsigned u = __builtin_bit_cast(unsigned, f);
    u += 0x7fffu + ((u >> 16) & 1u);   // RNE
    return (unsigned short)(u >> 16);
}
__device__ __forceinline__ float bf2f(unsigned short s) {
    return __builtin_bit_cast(float, ((unsigned)s) << 16);
}
__device__ __forceinline__ float sigm(float x) {
    return __builtin_amdgcn_rcpf(1.0f + exp2f(-1.4426950408889634f * x));
}
__device__ __forceinline__ float tanh_f(float x) {
    return 1.0f - 2.0f * __builtin_amdgcn_rcpf(1.0f + exp2f(2.8853900817779268f * x));
}

// Weights bf16, layout [k8][col][8]: elem (col, k=k8*8+e) at (k8*256+col)*8+e.
// w0: 48 k8 (K=384); per gate wg: 80 k8 (K=640: h|x|s), gates f,i,T,u,o.
__global__ void convert_w(const float* __restrict__ Wh, const float* __restrict__ Wx,
                          const float* __restrict__ Ws, unsigned short* __restrict__ w0,
                          unsigned short* __restrict__ wg) {
    const int t  = blockIdx.x * blockDim.x + threadIdx.x;
    const int N0 = 48 * 2048;        // 98304
    const int N1 = 5 * 80 * 2048;    // 819200
    if (t < N0) {
        const int k8 = t >> 11, rem = t & 2047;
        const int col = rem >> 3, e = rem & 7;
        const int k = k8 * 8 + e;
        const float v = (k < H) ? Wh[col * H + k] : Wx[col * I + (k - H)];
        w0[t] = f2bf(v);
    } else if (t < N0 + N1) {
        const int u   = t - N0;
        const int g1  = u / 163840;
        const int rem = u - g1 * 163840;
        const int k8  = rem >> 11;
        const int r2  = rem & 2047;
        const int col = r2 >> 3, e = r2 & 7;
        const int k   = k8 * 8 + e;
        const int g   = g1 + 1;
        float v;
        if (k < H)        v = Wh[g * H * H + col * H + k];
        else if (k < K1)  v = Wx[g * H * I + col * I + (k - H)];
        else              v = Ws[g1 * H * H + col * H + (k - K1)];
        wg[u] = f2bf(v);
    }
}

// Single-gate K-loop (s and o passes): 1 A + 1 B stream, ring depth 2.
template<int NIT>
__device__ __forceinline__ void gemm1(const unsigned char* Ab, int abase,
        const unsigned short* __restrict__ Wp, f32x16& acc) {
    bf16x8 b[2], a[2];
    #pragma unroll
    for (int i = 0; i < 2; ++i) {
        b[i] = *(const bf16x8*)(Wp + i * 4096);
        a[i] = *(const bf16x8*)(Ab + abase + i * 1024);
    }
    #pragma unroll
    for (int i = 0; i < NIT; ++i) {
        const bf16x8 av = a[i & 1], bv = b[i & 1];
        if (i + 2 < NIT) {
            a[i & 1] = *(const bf16x8*)(Ab + abase + (i + 2) * 1024);
            b[i & 1] = *(const bf16x8*)(Wp + (i + 2) * 4096);
        }
        acc = __builtin_amdgcn_mfma_f32_32x32x16_bf16(av, bv, acc, 0, 0, 0);
    }
}

// Gate-pair K-loop: 1 shared A stream, 2 B streams (two gates), 2 accs.
template<int NIT>
__device__ __forceinline__ void gemm2g(const unsigned char* Ab, int abase,
        const unsigned short* __restrict__ Wp0, const unsigned short* __restrict__ Wp1,
        f32x16& acc0, f32x16& acc1) {
    bf16x8 b0[2], b1[2], a[2];
    #pragma unroll
    for (int i = 0; i < 2; ++i) {
        b0[i] = *(const bf16x8*)(Wp0 + i * 4096);
        b1[i] = *(const bf16x8*)(Wp1 + i * 4096);
        a[i]  = *(const bf16x8*)(Ab + abase + i * 1024);
    }
    #pragma unroll
    for (int i = 0; i < NIT; ++i) {
        const bf16x8 av = a[i & 1], bv0 = b0[i & 1], bv1 = b1[i & 1];
        if (i + 2 < NIT) {
            a[i & 1]  = *(const bf16x8*)(Ab + abase + (i + 2) * 1024);
            b0[i & 1] = *(const bf16x8*)(Wp0 + (i + 2) * 4096);
            b1[i & 1] = *(const bf16x8*)(Wp1 + (i + 2) * 4096);
        }
        acc0 = __builtin_amdgcn_mfma_f32_32x32x16_bf16(av, bv0, acc0, 0, 0, 0);
        acc1 = __builtin_amdgcn_mfma_f32_32x32x16_bf16(av, bv1, acc1, 0, 0, 0);
    }
}

__global__ __launch_bounds__(NTHR, 4) void thlstm_fused(
        const float* __restrict__ x_t, const float* __restrict__ delta_t,
        const float* __restrict__ h_prev, const float* __restrict__ c_prev,
        const float* __restrict__ Wst, const float* __restrict__ bias,
        const unsigned short* __restrict__ w0, const unsigned short* __restrict__ wg,
        float* __restrict__ out) {
    __shared__ __align__(16) unsigned char Abuf[114688];  // 80KB A + 32KB c
    const int tid = threadIdx.x;
    const int b0  = blockIdx.x * BT;

    // ---- stage h|x bf16: region(row>>5), chunk (k8, row&31) ----
    #pragma unroll
    for (int it = 0; it < 3; ++it) {
        const int c   = it * NTHR + tid;
        const int k8  = c >> 6, row = c & 63;
        const float* src = (k8 < 32) ? (h_prev + (size_t)(b0 + row) * H + k8 * 8)
                                     : (x_t    + (size_t)(b0 + row) * I + (k8 - 32) * 8);
        const float4 v0 = ((const float4*)src)[0];
        const float4 v1 = ((const float4*)src)[1];
        ushort8 p;
        p[0] = f2bf(v0.x); p[1] = f2bf(v0.y); p[2] = f2bf(v0.z); p[3] = f2bf(v0.w);
        p[4] = f2bf(v1.x); p[5] = f2bf(v1.y); p[6] = f2bf(v1.z); p[7] = f2bf(v1.w);
        *(ushort8*)(Abuf + (row >> 5) * REG1 + (k8 * 32 + (row & 31)) * 16) = p;
    }
    __syncthreads();

    const int lane  = tid & 63;
    const int wv    = tid >> 6;            // 0..15
    const int rg    = wv >> 3;             // row region 0/1
    const int half  = lane >> 5;
    const int l31   = lane & 31;
    const int ocol  = (wv & 7) * 32 + l31;
    const int rowb  = rg * 32;
    const int rbase = 4 * half;
    const int abase = rg * REG1 + half * 512 + l31 * 16;
    const int wlo   = half * 2048 + ocol * 8;   // shorts
    const int sbase = rg * REG1 + SOFF + ((ocol >> 3) * 32) * 16 + (ocol & 7) * 2;
    const int cbase = COFF + (ocol >> 3) * 1024 + (ocol & 7) * 2;   // + grow*16

    // ---- gate s: K=384 ----
    {
        f32x16 acc;
        #pragma unroll
        for (int r = 0; r < 16; ++r) acc[r] = 0.f;
        gemm1<24>(Abuf, abase, w0 + wlo, acc);
        const float wst = Wst[ocol];
        const float bs  = bias[ocol];
        #pragma unroll
        for (int r = 0; r < 16; ++r) {
            const int mrow = (r & 3) + 8 * (r >> 2) + rbase;
            const float sv = tanh_f(acc[r] + delta_t[b0 + rowb + mrow] * wst + bs);
            *(unsigned short*)(Abuf + sbase + mrow * 16) = f2bf(sv);
        }
    }
    __syncthreads();

    // ---- pass A: gates f (wg0, bias1) + T (wg2, bias3): c = f*c_prev + T*s ----
    {
        f32x16 acf, acT;
        #pragma unroll
        for (int r = 0; r < 16; ++r) { acf[r] = 0.f; acT[r] = 0.f; }
        gemm2g<40>(Abuf, abase, wg + 0 * 163840 + wlo, wg + 2 * 163840 + wlo, acf, acT);
        const float bgf = bias[1 * H + ocol];
        const float bgT = bias[3 * H + ocol];
        #pragma unroll
        for (int r = 0; r < 16; ++r) {
            const int mrow = (r & 3) + 8 * (r >> 2) + rbase;
            const int grow = rowb + mrow;
            const size_t idx = (size_t)(b0 + grow) * H + ocol;
            const float sv = bf2f(*(const unsigned short*)(Abuf + sbase + mrow * 16));
            const float cv = sigm(acf[r] + bgf) * c_prev[idx] + sigm(acT[r] + bgT) * sv;
            *(unsigned short*)(Abuf + cbase + grow * 16) = f2bf(cv);
        }
    }
    // ---- pass B: gates i (wg1, bias2) + u (wg3, bias4): c += sigm(i)*tanh(u) ----
    {
        f32x16 aci, acu;
        #pragma unroll
        for (int r = 0; r < 16; ++r) { aci[r] = 0.f; acu[r] = 0.f; }
        gemm2g<40>(Abuf, abase, wg + 1 * 163840 + wlo, wg + 3 * 163840 + wlo, aci, acu);
        const float bgi = bias[2 * H + ocol];
        const float bgu = bias[4 * H + ocol];
        #pragma unroll
        for (int r = 0; r < 16; ++r) {
            const int mrow = (r & 3) + 8 * (r >> 2) + rbase;
            const int grow = rowb + mrow;
            const float co = bf2f(*(const unsigned short*)(Abuf + cbase + grow * 16));
            const float cv = co + sigm(aci[r] + bgi) * tanh_f(acu[r] + bgu);
            *(unsigned short*)(Abuf + cbase + grow * 16) = f2bf(cv);
        }
    }
    // ---- pass C: gate o (wg4, bias5): outputs ----
    {
        f32x16 ac;
        #pragma unroll
        for (int r = 0; r < 16; ++r) ac[r] = 0.f;
        gemm1<40>(Abuf, abase, wg + 4 * 163840 + wlo, ac);
        const float bg = bias[5 * H + ocol];
        #pragma unroll
        for (int r = 0; r < 16; ++r) {
            const int mrow = (r & 3) + 8 * (r >> 2) + rbase;
            const int grow = rowb + mrow;
            const size_t idx = (size_t)(b0 + grow) * H + ocol;
            const float c = bf2f(*(const unsigned short*)(Abuf + cbase + grow * 16));
            out[idx] = sigm(ac[r] + bg) * tanh_f(c);
            out[(size_t)Btot * H + idx] = c;
        }
    }
}

extern "C" void kernel_launch(void* const* d_in, const int* in_sizes, int n_in,
                              void* d_out, int out_size, void* d_ws, size_t ws_size,
                              hipStream_t stream) {
    (void)in_sizes; (void)n_in; (void)out_size; (void)ws_size;
    const float* x_t    = (const float*)d_in[0];
    const float* delta  = (const float*)d_in[1];
    const float* h_prev = (const float*)d_in[2];
    const float* c_prev = (const float*)d_in[3];
    const float* Wh     = (const float*)d_in[4];
    const float* Wx     = (const float*)d_in[5];
    const float* Ws     = (const float*)d_in[6];
    const float* Wst    = (const float*)d_in[7];
    const float* bias   = (const float*)d_in[8];
    float* out = (float*)d_out;

    unsigned short* w0 = (unsigned short*)d_ws;   // 48*2048 bf16
    unsigned short* wg = w0 + 48 * 2048;          // 5*80*2048 bf16

    const int total = 48 * 2048 + 5 * 80 * 2048;  // 917504
    convert_w<<<(total + 255) / 256, 256, 0, stream>>>(Wh, Wx, Ws, w0, wg);
    thlstm_fused<<<Btot / BT, NTHR, 0, stream>>>(x_t, delta, h_prev, c_prev,
                                                 Wst, bias, w0, wg, out);
}